// Round 8
// baseline (608.805 us; speedup 1.0000x reference)
//
#include <hip/hip_runtime.h>
#include <hip/hip_bf16.h>
#include <math.h>

// Causal SDPA, B=2 H=16 S=2048 D=64, fp32 in/out.
// v6b: QBLK=64, 8 waves = 2 q-strips x 4 kv-quarters (split-KV x4, KVBLK=32),
// grid 1024 blocks (8192 waves = 100% slots), 4 blocks/CU target.
// Packed V^T [32][64]. XCD-affine grid. T12 in-reg P, T13 deferred rescale.
// 2-stage merge tree through LDS overlaid on staging buffers.
// (v6 compile fix: no static array of LDS pointers -> runtime slot select.)

#define S_LEN 2048
#define D_DIM 64
#define NTH   512
#define L2E   1.4426950408889634f
#define THRL2 11.5f

typedef float f32x16 __attribute__((ext_vector_type(16)));
typedef __bf16 bf16x8 __attribute__((ext_vector_type(8)));
typedef __bf16 bf16x4 __attribute__((ext_vector_type(4)));
typedef unsigned int uint2v __attribute__((ext_vector_type(2)));

static __device__ inline unsigned int cvtpk(float lo, float hi) {
  unsigned int r;
  asm("v_cvt_pk_bf16_f32 %0, %1, %2" : "=v"(r) : "v"(lo), "v"(hi));
  return r;
}
// swizzled element offset in a [rows][64] bf16 LDS tile (128B rows)
static __device__ inline int swz(int row, int col) {
  return row * 64 + ((((col >> 3) ^ (row & 7)) << 3) | (col & 7));
}

__global__ __launch_bounds__(NTH, 8) void attn_fwd_kernel(
    const float* __restrict__ Qg, const float* __restrict__ Kg,
    const float* __restrict__ Vg, float* __restrict__ Og) {
  __shared__ unsigned short lds_k[4][32 * 64];   // per-quarter K[kv][d]
  __shared__ unsigned short lds_v[4][32 * 64];   // per-quarter packed V^T
  __shared__ float lds_ml[4][64][2];             // merge m,l slots

  const int t = threadIdx.x;
  const int lane = t & 63, w = t >> 6, l31 = lane & 31, h = lane >> 5;
  const int wq = w & 1, qt = w >> 1;   // q-strip 0..1, kv-quarter 0..3
  const int tl = t & 127;              // staging index within quarter group
  const int qts = t >> 7;              // staging quarter (== qt)

  const int wgid = (int)blockIdx.x;
  const int xcd = wgid & 7, idx = wgid >> 3;
  const int bh = xcd * 4 + (idx >> 5);           // 4 heads per XCD
  const int q0 = (31 - (idx & 31)) * 64;         // descending q (big first)
  const size_t base = (size_t)bh * S_LEN * D_DIM;
  const float* Q = Qg + base;
  const float* K = Kg + base;
  const float* V = Vg + base;
  float*       O = Og + base;

  const int qrow_w = q0 + wq * 32;
  const int qg = qrow_w + l31;          // this lane's q-row

  // ---- Q fragments (B operand: col q = lane&31, k = h*8+j), x0.125 ----
  bf16x8 qf[4];
  {
    const float* qp = Q + (size_t)qg * D_DIM + h * 8;
#pragma unroll
    for (int kc = 0; kc < 4; ++kc) {
      float4 a = *(const float4*)(qp + kc * 16);
      float4 b = *(const float4*)(qp + kc * 16 + 4);
      bf16x8 q8;
      q8[0] = (__bf16)(a.x * 0.125f); q8[1] = (__bf16)(a.y * 0.125f);
      q8[2] = (__bf16)(a.z * 0.125f); q8[3] = (__bf16)(a.w * 0.125f);
      q8[4] = (__bf16)(b.x * 0.125f); q8[5] = (__bf16)(b.y * 0.125f);
      q8[6] = (__bf16)(b.z * 0.125f); q8[7] = (__bf16)(b.w * 0.125f);
      qf[kc] = q8;
    }
  }

  float mL2 = -INFINITY, lsum = 0.0f;   // per-lane (q = l31) softmax state
  f32x16 acc0 = (f32x16)0.0f, acc1 = (f32x16)0.0f;   // O[32q][32d] halves

  const int nit = q0 / 128 + 1;         // 128-wide kv super-tiles
  for (int it = 0; it < nit; ++it) {
    __syncthreads();                    // previous reads done (all waves)

    // ---- stage this quarter's K[32][64] + packed V^T[32][64] ----
    const int kv0s = it * 128 + qts * 32;
#pragma unroll
    for (int pass = 0; pass < 4; ++pass) {
      int row = pass * 8 + (tl >> 4);
      int c4  = (tl & 15) * 4;
      float4 f = *(const float4*)(K + (size_t)(kv0s + row) * D_DIM + c4);
      bf16x4 k4;
      k4[0] = (__bf16)f.x; k4[1] = (__bf16)f.y;
      k4[2] = (__bf16)f.z; k4[3] = (__bf16)f.w;
      *(bf16x4*)&lds_k[qts][swz(row, c4)] = k4;
    }
    {
      int d2 = (tl & 31) * 2, kvo = tl >> 5;   // d pair, kv octet 0..3
      float2 vv[8];
#pragma unroll
      for (int i = 0; i < 8; ++i)
        vv[i] = *(const float2*)(V + (size_t)(kv0s + kvo * 8 + i) * D_DIM + d2);
      bf16x8 bx, by;
#pragma unroll
      for (int i = 0; i < 8; ++i) {
        bx[i] = (__bf16)vv[i].x;
        by[i] = (__bf16)vv[i].y;
      }
      // packed row = d>>1, col = (d&1)*32 + kv
      *(bf16x8*)&lds_v[qts][swz(tl & 31, kvo * 8)]      = bx;
      *(bf16x8*)&lds_v[qts][swz(tl & 31, 32 + kvo * 8)] = by;
    }
    __syncthreads();                    // tile staged

    const int kv0 = it * 128 + qt * 32;
    if (kv0 > qrow_w) continue;         // fully masked for this wave

    // ---- S^T = K·Q^T : D[32kv][32q], lane owns col q = l31 ----
    f32x16 st = (f32x16)0.0f;
#pragma unroll
    for (int kc = 0; kc < 4; ++kc) {
      bf16x8 kf = *(const bf16x8*)&lds_k[qt][swz(l31, kc * 16 + h * 8)];
      st = __builtin_amdgcn_mfma_f32_32x32x16_bf16(kf, qf[kc], st, 0, 0, 0);
    }

    // ---- causal mask (diagonal tile only) + row max ----
    float tm = -INFINITY;
    if (kv0 == qrow_w) {                // the one diagonal tile per strip
#pragma unroll
      for (int r = 0; r < 16; ++r) {
        int kv = kv0 + (r & 3) + 8 * (r >> 2) + 4 * h;
        float sv = (kv <= qg) ? st[r] : -INFINITY;
        st[r] = sv;
        tm = fmaxf(tm, sv);
      }
    } else {
#pragma unroll
      for (int r = 0; r < 16; ++r) tm = fmaxf(tm, st[r]);
    }
    tm = fmaxf(tm, __shfl_xor(tm, 32));
    const float tmL2 = tm * L2E;

    // ---- deferred rescale (T13) ----
    if (__any(tmL2 - mL2 > THRL2)) {
      const float mn = fmaxf(mL2, tmL2);
      const float f  = exp2f(mL2 - mn);
      lsum *= f;
      mL2 = mn;
#pragma unroll
      for (int r = 0; r < 16; ++r) {
        const int mrow = (r & 3) + 8 * (r >> 2) + 4 * h;
        const float fr = __shfl(f, mrow);
        acc0[r] *= fr;
        acc1[r] *= fr;
      }
    }

    // ---- P = exp2(S*L2E - m); row sum ----
    float ps = 0.0f;
#pragma unroll
    for (int r = 0; r < 16; ++r) {
      float p = exp2f(fmaf(st[r], L2E, -mL2));
      st[r] = p;
      ps += p;
    }
    ps += __shfl_xor(ps, 32);
    lsum += ps;

    // ---- PV: in-register A-frag via cvt_pk + permlane32_swap (T12) ----
#pragma unroll
    for (int c = 0; c < 2; ++c) {
      const int rb = 8 * c;
      unsigned int A0 = cvtpk(st[rb + 0], st[rb + 1]);
      unsigned int A1 = cvtpk(st[rb + 2], st[rb + 3]);
      unsigned int B0 = cvtpk(st[rb + 4], st[rb + 5]);
      unsigned int B1 = cvtpk(st[rb + 6], st[rb + 7]);
      unsigned int W0, W1, W2, W3;
#if __has_builtin(__builtin_amdgcn_permlane32_swap)
      {
        uint2v r02 = __builtin_amdgcn_permlane32_swap(A0, B0, false, false);
        uint2v r13 = __builtin_amdgcn_permlane32_swap(A1, B1, false, false);
        W0 = r02[0]; W2 = r02[1];
        W1 = r13[0]; W3 = r13[1];
      }
#else
      {
        unsigned int sA0 = (unsigned int)__shfl_xor((int)A0, 32);
        unsigned int sB0 = (unsigned int)__shfl_xor((int)B0, 32);
        unsigned int sA1 = (unsigned int)__shfl_xor((int)A1, 32);
        unsigned int sB1 = (unsigned int)__shfl_xor((int)B1, 32);
        W0 = h ? sB0 : A0;  W2 = h ? B0 : sA0;
        W1 = h ? sB1 : A1;  W3 = h ? B1 : sA1;
      }
#endif
      uint4 uw = { W0, W1, W2, W3 };
      bf16x8 pa = __builtin_bit_cast(bf16x8, uw);
#pragma unroll
      for (int dh = 0; dh < 2; ++dh) {
        // V[kv = c*16+h*8+j][d = dh*32+l31] at packed (row=d>>1, col=(d&1)*32+kv)
        bf16x8 vf = *(const bf16x8*)&lds_v[qt][
            swz(dh * 16 + (l31 >> 1), (l31 & 1) * 32 + c * 16 + h * 8)];
        if (dh == 0)
          acc0 = __builtin_amdgcn_mfma_f32_32x32x16_bf16(pa, vf, acc0, 0, 0, 0);
        else
          acc1 = __builtin_amdgcn_mfma_f32_32x32x16_bf16(pa, vf, acc1, 0, 0, 0);
      }
    }
  }

  // ---- 2-stage 4-way merge through LDS (overlay staging buffers) ----
  // merge slot s (0..3) -> float scratch [64][32] each
  __syncthreads();                      // last tile's LDS reads done
  if (qt & 1) {                         // stage A writers: qt 1,3
    const int s = (wq << 1) | (qt >> 1);
    lds_ml[s][lane][0] = mL2;
    lds_ml[s][lane][1] = lsum;
    float* a = (s < 2 ? (float*)&lds_k[(s & 1) * 2][0]
                      : (float*)&lds_v[(s & 1) * 2][0]) + lane * 32;
#pragma unroll
    for (int r = 0; r < 16; ++r) { a[r] = acc0[r]; a[16 + r] = acc1[r]; }
  }
  __syncthreads();
  if (!(qt & 1)) {                      // stage A readers: qt 0,2
    const int s = (wq << 1) | (qt >> 1);
    const float mB = lds_ml[s][lane][0];
    const float lB = lds_ml[s][lane][1];
    const float mst = fmaxf(mL2, mB);
    float fA, fB;
    if (mst == -INFINITY) { fA = 0.0f; fB = 0.0f; }
    else { fA = exp2f(mL2 - mst); fB = exp2f(mB - mst); }
    lsum = lsum * fA + lB * fB;
    mL2 = mst;
    const float* a = (s < 2 ? (const float*)&lds_k[(s & 1) * 2][0]
                            : (const float*)&lds_v[(s & 1) * 2][0]) + lane * 32;
#pragma unroll
    for (int r = 0; r < 16; ++r) {
      const int mrow = (r & 3) + 8 * (r >> 2) + 4 * h;
      const float fAr = __shfl(fA, mrow);
      const float fBr = __shfl(fB, mrow);
      acc0[r] = acc0[r] * fAr + a[r] * fBr;
      acc1[r] = acc1[r] * fAr + a[16 + r] * fBr;
    }
  }
  __syncthreads();
  if (qt == 2) {                        // stage B writer
    const int s = (wq << 1) | 1;
    lds_ml[s][lane][0] = mL2;
    lds_ml[s][lane][1] = lsum;
    float* a = (s < 2 ? (float*)&lds_k[(s & 1) * 2][0]
                      : (float*)&lds_v[(s & 1) * 2][0]) + lane * 32;
#pragma unroll
    for (int r = 0; r < 16; ++r) { a[r] = acc0[r]; a[16 + r] = acc1[r]; }
  }
  __syncthreads();
  if (qt == 0) {                        // stage B reader + O write
    const int s = (wq << 1) | 1;
    const float mB = lds_ml[s][lane][0];
    const float lB = lds_ml[s][lane][1];
    const float mst = fmaxf(mL2, mB);
    float fA, fB;
    if (mst == -INFINITY) { fA = 0.0f; fB = 0.0f; }
    else { fA = exp2f(mL2 - mst); fB = exp2f(mB - mst); }
    const float lm = lsum * fA + lB * fB;
    const float li = 1.0f / lm;
    const float* a = (s < 2 ? (const float*)&lds_k[(s & 1) * 2][0]
                            : (const float*)&lds_v[(s & 1) * 2][0]) + lane * 32;
#pragma unroll
    for (int r = 0; r < 16; ++r) {
      const int mrow = (r & 3) + 8 * (r >> 2) + 4 * h;
      const float fAr = __shfl(fA, mrow);
      const float fBr = __shfl(fB, mrow);
      const float lr  = __shfl(li, mrow);
      const float o0 = (acc0[r] * fAr + a[r] * fBr) * lr;
      const float o1 = (acc1[r] * fAr + a[16 + r] * fBr) * lr;
      float* op = O + (size_t)(qrow_w + mrow) * D_DIM + l31;
      op[0]  = o0;
      op[32] = o1;
    }
  }
}

extern "C" void kernel_launch(void* const* d_in, const int* in_sizes, int n_in,
                              void* d_out, int out_size, void* d_ws, size_t ws_size,
                              hipStream_t stream) {
  const float* q = (const float*)d_in[0];
  const float* k = (const float*)d_in[1];
  const float* v = (const float*)d_in[2];
  // d_in[3] (causal mask) is deterministic tril -> computed in-kernel.
  float* o = (float*)d_out;
  attn_fwd_kernel<<<1024, NTH, 0, stream>>>(q, k, v, o);
}

// Round 9
// 109.847 us; speedup vs baseline: 5.5423x; 5.5423x over previous
//
#include <hip/hip_runtime.h>
#include <hip/hip_bf16.h>
#include <math.h>

// Causal SDPA, B=2 H=16 S=2048 D=64, fp32 in/out.
// v7: v6b with the occupancy bound reverted to (512,4). v6's (512,8) forced
// a 64-VGPR cap -> allocator crushed to 32 VGPR and spilled acc/st to
// scratch (832 MB writes, 7x regression). 128-VGPR cap fits the ~100-reg
// live set with zero spills; 2 blocks/CU resident, grid 1024 backfills.

#define S_LEN 2048
#define D_DIM 64
#define NTH   512
#define L2E   1.4426950408889634f
#define THRL2 11.5f

typedef float f32x16 __attribute__((ext_vector_type(16)));
typedef __bf16 bf16x8 __attribute__((ext_vector_type(8)));
typedef __bf16 bf16x4 __attribute__((ext_vector_type(4)));
typedef unsigned int uint2v __attribute__((ext_vector_type(2)));

static __device__ inline unsigned int cvtpk(float lo, float hi) {
  unsigned int r;
  asm("v_cvt_pk_bf16_f32 %0, %1, %2" : "=v"(r) : "v"(lo), "v"(hi));
  return r;
}
// swizzled element offset in a [rows][64] bf16 LDS tile (128B rows)
static __device__ inline int swz(int row, int col) {
  return row * 64 + ((((col >> 3) ^ (row & 7)) << 3) | (col & 7));
}

__global__ __launch_bounds__(NTH, 4) void attn_fwd_kernel(
    const float* __restrict__ Qg, const float* __restrict__ Kg,
    const float* __restrict__ Vg, float* __restrict__ Og) {
  __shared__ unsigned short lds_k[4][32 * 64];   // per-quarter K[kv][d]
  __shared__ unsigned short lds_v[4][32 * 64];   // per-quarter packed V^T
  __shared__ float lds_ml[4][64][2];             // merge m,l slots

  const int t = threadIdx.x;
  const int lane = t & 63, w = t >> 6, l31 = lane & 31, h = lane >> 5;
  const int wq = w & 1, qt = w >> 1;   // q-strip 0..1, kv-quarter 0..3
  const int tl = t & 127;              // staging index within quarter group
  const int qts = t >> 7;              // staging quarter (== qt)

  const int wgid = (int)blockIdx.x;
  const int xcd = wgid & 7, idx = wgid >> 3;
  const int bh = xcd * 4 + (idx >> 5);           // 4 heads per XCD
  const int q0 = (31 - (idx & 31)) * 64;         // descending q (big first)
  const size_t base = (size_t)bh * S_LEN * D_DIM;
  const float* Q = Qg + base;
  const float* K = Kg + base;
  const float* V = Vg + base;
  float*       O = Og + base;

  const int qrow_w = q0 + wq * 32;
  const int qg = qrow_w + l31;          // this lane's q-row

  // ---- Q fragments (B operand: col q = lane&31, k = h*8+j), x0.125 ----
  bf16x8 qf[4];
  {
    const float* qp = Q + (size_t)qg * D_DIM + h * 8;
#pragma unroll
    for (int kc = 0; kc < 4; ++kc) {
      float4 a = *(const float4*)(qp + kc * 16);
      float4 b = *(const float4*)(qp + kc * 16 + 4);
      bf16x8 q8;
      q8[0] = (__bf16)(a.x * 0.125f); q8[1] = (__bf16)(a.y * 0.125f);
      q8[2] = (__bf16)(a.z * 0.125f); q8[3] = (__bf16)(a.w * 0.125f);
      q8[4] = (__bf16)(b.x * 0.125f); q8[5] = (__bf16)(b.y * 0.125f);
      q8[6] = (__bf16)(b.z * 0.125f); q8[7] = (__bf16)(b.w * 0.125f);
      qf[kc] = q8;
    }
  }

  float mL2 = -INFINITY, lsum = 0.0f;   // per-lane (q = l31) softmax state
  f32x16 acc0 = (f32x16)0.0f, acc1 = (f32x16)0.0f;   // O[32q][32d] halves

  const int nit = q0 / 128 + 1;         // 128-wide kv super-tiles
  for (int it = 0; it < nit; ++it) {
    __syncthreads();                    // previous reads done (all waves)

    // ---- stage this quarter's K[32][64] + packed V^T[32][64] ----
    const int kv0s = it * 128 + qts * 32;
#pragma unroll
    for (int pass = 0; pass < 4; ++pass) {
      int row = pass * 8 + (tl >> 4);
      int c4  = (tl & 15) * 4;
      float4 f = *(const float4*)(K + (size_t)(kv0s + row) * D_DIM + c4);
      bf16x4 k4;
      k4[0] = (__bf16)f.x; k4[1] = (__bf16)f.y;
      k4[2] = (__bf16)f.z; k4[3] = (__bf16)f.w;
      *(bf16x4*)&lds_k[qts][swz(row, c4)] = k4;
    }
    {
      int d2 = (tl & 31) * 2, kvo = tl >> 5;   // d pair, kv octet 0..3
      float2 vv[8];
#pragma unroll
      for (int i = 0; i < 8; ++i)
        vv[i] = *(const float2*)(V + (size_t)(kv0s + kvo * 8 + i) * D_DIM + d2);
      bf16x8 bx, by;
#pragma unroll
      for (int i = 0; i < 8; ++i) {
        bx[i] = (__bf16)vv[i].x;
        by[i] = (__bf16)vv[i].y;
      }
      // packed row = d>>1, col = (d&1)*32 + kv
      *(bf16x8*)&lds_v[qts][swz(tl & 31, kvo * 8)]      = bx;
      *(bf16x8*)&lds_v[qts][swz(tl & 31, 32 + kvo * 8)] = by;
    }
    __syncthreads();                    // tile staged

    const int kv0 = it * 128 + qt * 32;
    if (kv0 > qrow_w) continue;         // fully masked for this wave

    // ---- S^T = K·Q^T : D[32kv][32q], lane owns col q = l31 ----
    f32x16 st = (f32x16)0.0f;
#pragma unroll
    for (int kc = 0; kc < 4; ++kc) {
      bf16x8 kf = *(const bf16x8*)&lds_k[qt][swz(l31, kc * 16 + h * 8)];
      st = __builtin_amdgcn_mfma_f32_32x32x16_bf16(kf, qf[kc], st, 0, 0, 0);
    }

    // ---- causal mask (diagonal tile only) + row max ----
    float tm = -INFINITY;
    if (kv0 == qrow_w) {                // the one diagonal tile per strip
#pragma unroll
      for (int r = 0; r < 16; ++r) {
        int kv = kv0 + (r & 3) + 8 * (r >> 2) + 4 * h;
        float sv = (kv <= qg) ? st[r] : -INFINITY;
        st[r] = sv;
        tm = fmaxf(tm, sv);
      }
    } else {
#pragma unroll
      for (int r = 0; r < 16; ++r) tm = fmaxf(tm, st[r]);
    }
    tm = fmaxf(tm, __shfl_xor(tm, 32));
    const float tmL2 = tm * L2E;

    // ---- deferred rescale (T13) ----
    if (__any(tmL2 - mL2 > THRL2)) {
      const float mn = fmaxf(mL2, tmL2);
      const float f  = exp2f(mL2 - mn);
      lsum *= f;
      mL2 = mn;
#pragma unroll
      for (int r = 0; r < 16; ++r) {
        const int mrow = (r & 3) + 8 * (r >> 2) + 4 * h;
        const float fr = __shfl(f, mrow);
        acc0[r] *= fr;
        acc1[r] *= fr;
      }
    }

    // ---- P = exp2(S*L2E - m); row sum ----
    float ps = 0.0f;
#pragma unroll
    for (int r = 0; r < 16; ++r) {
      float p = exp2f(fmaf(st[r], L2E, -mL2));
      st[r] = p;
      ps += p;
    }
    ps += __shfl_xor(ps, 32);
    lsum += ps;

    // ---- PV: in-register A-frag via cvt_pk + permlane32_swap (T12) ----
#pragma unroll
    for (int c = 0; c < 2; ++c) {
      const int rb = 8 * c;
      unsigned int A0 = cvtpk(st[rb + 0], st[rb + 1]);
      unsigned int A1 = cvtpk(st[rb + 2], st[rb + 3]);
      unsigned int B0 = cvtpk(st[rb + 4], st[rb + 5]);
      unsigned int B1 = cvtpk(st[rb + 6], st[rb + 7]);
      unsigned int W0, W1, W2, W3;
#if __has_builtin(__builtin_amdgcn_permlane32_swap)
      {
        uint2v r02 = __builtin_amdgcn_permlane32_swap(A0, B0, false, false);
        uint2v r13 = __builtin_amdgcn_permlane32_swap(A1, B1, false, false);
        W0 = r02[0]; W2 = r02[1];
        W1 = r13[0]; W3 = r13[1];
      }
#else
      {
        unsigned int sA0 = (unsigned int)__shfl_xor((int)A0, 32);
        unsigned int sB0 = (unsigned int)__shfl_xor((int)B0, 32);
        unsigned int sA1 = (unsigned int)__shfl_xor((int)A1, 32);
        unsigned int sB1 = (unsigned int)__shfl_xor((int)B1, 32);
        W0 = h ? sB0 : A0;  W2 = h ? B0 : sA0;
        W1 = h ? sB1 : A1;  W3 = h ? B1 : sA1;
      }
#endif
      uint4 uw = { W0, W1, W2, W3 };
      bf16x8 pa = __builtin_bit_cast(bf16x8, uw);
#pragma unroll
      for (int dh = 0; dh < 2; ++dh) {
        // V[kv = c*16+h*8+j][d = dh*32+l31] at packed (row=d>>1, col=(d&1)*32+kv)
        bf16x8 vf = *(const bf16x8*)&lds_v[qt][
            swz(dh * 16 + (l31 >> 1), (l31 & 1) * 32 + c * 16 + h * 8)];
        if (dh == 0)
          acc0 = __builtin_amdgcn_mfma_f32_32x32x16_bf16(pa, vf, acc0, 0, 0, 0);
        else
          acc1 = __builtin_amdgcn_mfma_f32_32x32x16_bf16(pa, vf, acc1, 0, 0, 0);
      }
    }
  }

  // ---- 2-stage 4-way merge through LDS (overlay staging buffers) ----
  // merge slot s (0..3) -> float scratch [64][32] each
  __syncthreads();                      // last tile's LDS reads done
  if (qt & 1) {                         // stage A writers: qt 1,3
    const int s = (wq << 1) | (qt >> 1);
    lds_ml[s][lane][0] = mL2;
    lds_ml[s][lane][1] = lsum;
    float* a = (s < 2 ? (float*)&lds_k[(s & 1) * 2][0]
                      : (float*)&lds_v[(s & 1) * 2][0]) + lane * 32;
#pragma unroll
    for (int r = 0; r < 16; ++r) { a[r] = acc0[r]; a[16 + r] = acc1[r]; }
  }
  __syncthreads();
  if (!(qt & 1)) {                      // stage A readers: qt 0,2
    const int s = (wq << 1) | (qt >> 1);
    const float mB = lds_ml[s][lane][0];
    const float lB = lds_ml[s][lane][1];
    const float mst = fmaxf(mL2, mB);
    float fA, fB;
    if (mst == -INFINITY) { fA = 0.0f; fB = 0.0f; }
    else { fA = exp2f(mL2 - mst); fB = exp2f(mB - mst); }
    lsum = lsum * fA + lB * fB;
    mL2 = mst;
    const float* a = (s < 2 ? (const float*)&lds_k[(s & 1) * 2][0]
                            : (const float*)&lds_v[(s & 1) * 2][0]) + lane * 32;
#pragma unroll
    for (int r = 0; r < 16; ++r) {
      const int mrow = (r & 3) + 8 * (r >> 2) + 4 * h;
      const float fAr = __shfl(fA, mrow);
      const float fBr = __shfl(fB, mrow);
      acc0[r] = acc0[r] * fAr + a[r] * fBr;
      acc1[r] = acc1[r] * fAr + a[16 + r] * fBr;
    }
  }
  __syncthreads();
  if (qt == 2) {                        // stage B writer
    const int s = (wq << 1) | 1;
    lds_ml[s][lane][0] = mL2;
    lds_ml[s][lane][1] = lsum;
    float* a = (s < 2 ? (float*)&lds_k[(s & 1) * 2][0]
                      : (float*)&lds_v[(s & 1) * 2][0]) + lane * 32;
#pragma unroll
    for (int r = 0; r < 16; ++r) { a[r] = acc0[r]; a[16 + r] = acc1[r]; }
  }
  __syncthreads();
  if (qt == 0) {                        // stage B reader + O write
    const int s = (wq << 1) | 1;
    const float mB = lds_ml[s][lane][0];
    const float lB = lds_ml[s][lane][1];
    const float mst = fmaxf(mL2, mB);
    float fA, fB;
    if (mst == -INFINITY) { fA = 0.0f; fB = 0.0f; }
    else { fA = exp2f(mL2 - mst); fB = exp2f(mB - mst); }
    const float lm = lsum * fA + lB * fB;
    const float li = 1.0f / lm;
    const float* a = (s < 2 ? (const float*)&lds_k[(s & 1) * 2][0]
                            : (const float*)&lds_v[(s & 1) * 2][0]) + lane * 32;
#pragma unroll
    for (int r = 0; r < 16; ++r) {
      const int mrow = (r & 3) + 8 * (r >> 2) + 4 * h;
      const float fAr = __shfl(fA, mrow);
      const float fBr = __shfl(fB, mrow);
      const float lr  = __shfl(li, mrow);
      const float o0 = (acc0[r] * fAr + a[r] * fBr) * lr;
      const float o1 = (acc1[r] * fAr + a[16 + r] * fBr) * lr;
      float* op = O + (size_t)(qrow_w + mrow) * D_DIM + l31;
      op[0]  = o0;
      op[32] = o1;
    }
  }
}

extern "C" void kernel_launch(void* const* d_in, const int* in_sizes, int n_in,
                              void* d_out, int out_size, void* d_ws, size_t ws_size,
                              hipStream_t stream) {
  const float* q = (const float*)d_in[0];
  const float* k = (const float*)d_in[1];
  const float* v = (const float*)d_in[2];
  // d_in[3] (causal mask) is deterministic tril -> computed in-kernel.
  float* o = (float*)d_out;
  attn_fwd_kernel<<<1024, NTH, 0, stream>>>(q, k, v, o);
}

// Round 10
// 109.711 us; speedup vs baseline: 5.5492x; 1.0012x over previous
//
#include <hip/hip_runtime.h>
#include <hip/hip_bf16.h>
#include <math.h>

// Causal SDPA, B=2 H=16 S=2048 D=64, fp32 in/out.
// v8: v5 structure (KVBLK=64, split-KV x2, 8 waves) with:
//  - complementary q-strip pairing: block owns strips p and 31-p ->
//    uniform ~16 super-tiles/block, shared KV staging for both strips
//  - T14 async-stage split: prologue reg-load; per iter
//    {barrier; ds_write; barrier; issue loads(it+1); compute}
//  - XCD-affine 1D grid (kept from v7: FETCH 116->24.6 MB)
//  - T5 setprio around MFMA clusters
// Waves: w&1 = strip (A=p, B=31-p), (w>>1)&1 = q-subwave, w>>2 = kv half.

#define S_LEN 2048
#define D_DIM 64
#define NTH   512
#define L2E   1.4426950408889634f
#define THRL2 11.5f

typedef float f32x16 __attribute__((ext_vector_type(16)));
typedef __bf16 bf16x8 __attribute__((ext_vector_type(8)));
typedef __bf16 bf16x4 __attribute__((ext_vector_type(4)));
typedef unsigned int uint2v __attribute__((ext_vector_type(2)));

static __device__ inline unsigned int cvtpk(float lo, float hi) {
  unsigned int r;
  asm("v_cvt_pk_bf16_f32 %0, %1, %2" : "=v"(r) : "v"(lo), "v"(hi));
  return r;
}
// swizzled element offset in a [rows][64] bf16 LDS tile (128B rows)
static __device__ inline int swz(int row, int col) {
  return row * 64 + ((((col >> 3) ^ (row & 7)) << 3) | (col & 7));
}

__global__ __launch_bounds__(NTH, 4) void attn_fwd_kernel(
    const float* __restrict__ Qg, const float* __restrict__ Kg,
    const float* __restrict__ Vg, float* __restrict__ Og) {
  __shared__ unsigned short lds_k[2][64 * 64];   // per-half K[kv][d] swizzled
  __shared__ unsigned short lds_v[2][64 * 64];   // per-half V^T[d][kv] swizzled
  __shared__ float lds_ml[4][64][2];             // merge m,l (half=1)

  const int t = threadIdx.x;
  const int lane = t & 63, w = t >> 6, l31 = lane & 31, h = lane >> 5;
  const int s = w & 1, qw = (w >> 1) & 1, half = w >> 2;
  const int pr = w & 3;                 // merge pair id (s,qw)
  const int tl = t & 255;               // staging index within half group

  const int wgid = (int)blockIdx.x;
  const int xcd = wgid & 7, idx = wgid >> 3;
  const int bh = xcd * 4 + (idx >> 4);  // 4 heads per XCD
  const int p  = idx & 15;              // strip pair: strips p and 31-p
  const int q0s = (s == 0 ? p : (31 - p)) * 64;
  const size_t base = (size_t)bh * S_LEN * D_DIM;
  const float* Q = Qg + base;
  const float* K = Kg + base;
  const float* V = Vg + base;
  float*       O = Og + base;

  const int qrow_w = q0s + qw * 32;
  const int qg = qrow_w + l31;          // this lane's q-row

  const int nit = (31 - p) / 2 + 1;     // uniform super-tile count (~16)

  // ---- Q fragments (B operand: col q = lane&31, k = h*8+j), x0.125 ----
  bf16x8 qf[4];
  {
    const float* qp = Q + (size_t)qg * D_DIM + h * 8;
#pragma unroll
    for (int kc = 0; kc < 4; ++kc) {
      float4 a = *(const float4*)(qp + kc * 16);
      float4 b = *(const float4*)(qp + kc * 16 + 4);
      bf16x8 q8;
      q8[0] = (__bf16)(a.x * 0.125f); q8[1] = (__bf16)(a.y * 0.125f);
      q8[2] = (__bf16)(a.z * 0.125f); q8[3] = (__bf16)(a.w * 0.125f);
      q8[4] = (__bf16)(b.x * 0.125f); q8[5] = (__bf16)(b.y * 0.125f);
      q8[6] = (__bf16)(b.z * 0.125f); q8[7] = (__bf16)(b.w * 0.125f);
      qf[kc] = q8;
    }
  }

  float mL2 = -INFINITY, lsum = 0.0f;   // per-lane (q = l31) softmax state
  f32x16 acc0 = (f32x16)0.0f, acc1 = (f32x16)0.0f;   // O[32q][32d] halves

  // ---- staging registers (T14: loaded one iteration ahead) ----
  float4 kreg[4];
  float2 vreg[8];
  const int srow = tl >> 4, sc4 = (tl & 15) * 4;     // K stage coords
  const int d2 = (tl & 31) * 2, kvq = tl >> 5;       // V stage coords

#define STAGE_LOAD(IT)                                                     \
  {                                                                        \
    const int kv0s = (IT) * 128 + half * 64;                               \
    _Pragma("unroll")                                                      \
    for (int pass = 0; pass < 4; ++pass)                                   \
      kreg[pass] = *(const float4*)(K + (size_t)(kv0s + pass * 16 + srow) * D_DIM + sc4); \
    _Pragma("unroll")                                                      \
    for (int i = 0; i < 8; ++i)                                            \
      vreg[i] = *(const float2*)(V + (size_t)(kv0s + kvq * 8 + i) * D_DIM + d2); \
  }

  STAGE_LOAD(0)

  for (int it = 0; it < nit; ++it) {
    __syncthreads();                    // previous tile's LDS reads done

    // ---- ds_write staged regs (loaded during previous compute) ----
#pragma unroll
    for (int pass = 0; pass < 4; ++pass) {
      bf16x4 k4;
      k4[0] = (__bf16)kreg[pass].x; k4[1] = (__bf16)kreg[pass].y;
      k4[2] = (__bf16)kreg[pass].z; k4[3] = (__bf16)kreg[pass].w;
      *(bf16x4*)&lds_k[half][swz(pass * 16 + srow, sc4)] = k4;
    }
    {
      bf16x8 bx, by;
#pragma unroll
      for (int i = 0; i < 8; ++i) {
        bx[i] = (__bf16)vreg[i].x;
        by[i] = (__bf16)vreg[i].y;
      }
      *(bf16x8*)&lds_v[half][swz(d2, kvq * 8)]     = bx;
      *(bf16x8*)&lds_v[half][swz(d2 + 1, kvq * 8)] = by;
    }
    __syncthreads();                    // tile staged

    // ---- issue next tile's global loads (hidden under compute) ----
    if (it + 1 < nit) STAGE_LOAD(it + 1)

    const int kv0 = it * 128 + half * 64;
    if (kv0 > qrow_w + 31) continue;    // fully masked for this wave

    // ---- S^T = K·Q^T : D[32kv][32q] x2 tiles, lane owns col q = l31 ----
    f32x16 st[2];
    st[0] = (f32x16)0.0f; st[1] = (f32x16)0.0f;
    __builtin_amdgcn_s_setprio(1);
#pragma unroll
    for (int kc = 0; kc < 4; ++kc) {
#pragma unroll
      for (int mt = 0; mt < 2; ++mt) {
        bf16x8 kf = *(const bf16x8*)&lds_k[half][swz(mt * 32 + l31, kc * 16 + h * 8)];
        st[mt] = __builtin_amdgcn_mfma_f32_32x32x16_bf16(kf, qf[kc], st[mt], 0, 0, 0);
      }
    }
    __builtin_amdgcn_s_setprio(0);

    // ---- causal mask (diagonal tiles only) + row max ----
    float tm = -INFINITY;
    if (kv0 + 63 > qrow_w) {            // tile touches the diagonal
#pragma unroll
      for (int mt = 0; mt < 2; ++mt)
#pragma unroll
        for (int r = 0; r < 16; ++r) {
          int kv = kv0 + mt * 32 + (r & 3) + 8 * (r >> 2) + 4 * h;
          float sv = (kv <= qg) ? st[mt][r] : -INFINITY;
          st[mt][r] = sv;
          tm = fmaxf(tm, sv);
        }
    } else {
#pragma unroll
      for (int mt = 0; mt < 2; ++mt)
#pragma unroll
        for (int r = 0; r < 16; ++r) tm = fmaxf(tm, st[mt][r]);
    }
    tm = fmaxf(tm, __shfl_xor(tm, 32));
    const float tmL2 = tm * L2E;

    // ---- deferred rescale (T13) ----
    if (__any(tmL2 - mL2 > THRL2)) {
      const float mn = fmaxf(mL2, tmL2);
      const float f  = exp2f(mL2 - mn);
      lsum *= f;
      mL2 = mn;
#pragma unroll
      for (int r = 0; r < 16; ++r) {
        const int mrow = (r & 3) + 8 * (r >> 2) + 4 * h;
        const float fr = __shfl(f, mrow);
        acc0[r] *= fr;
        acc1[r] *= fr;
      }
    }

    // ---- P = exp2(S*L2E - m); row sum ----
    float ps = 0.0f;
#pragma unroll
    for (int mt = 0; mt < 2; ++mt)
#pragma unroll
      for (int r = 0; r < 16; ++r) {
        float pv = exp2f(fmaf(st[mt][r], L2E, -mL2));
        st[mt][r] = pv;
        ps += pv;
      }
    ps += __shfl_xor(ps, 32);
    lsum += ps;

    // ---- PV: in-register A-frag via cvt_pk + permlane32_swap (T12) ----
#pragma unroll
    for (int c = 0; c < 4; ++c) {
      const int rb = 8 * (c & 1);
      const int m2 = c >> 1;
      unsigned int A0 = cvtpk(st[m2][rb + 0], st[m2][rb + 1]);
      unsigned int A1 = cvtpk(st[m2][rb + 2], st[m2][rb + 3]);
      unsigned int B0 = cvtpk(st[m2][rb + 4], st[m2][rb + 5]);
      unsigned int B1 = cvtpk(st[m2][rb + 6], st[m2][rb + 7]);
      unsigned int W0, W1, W2, W3;
#if __has_builtin(__builtin_amdgcn_permlane32_swap)
      {
        uint2v r02 = __builtin_amdgcn_permlane32_swap(A0, B0, false, false);
        uint2v r13 = __builtin_amdgcn_permlane32_swap(A1, B1, false, false);
        W0 = r02[0]; W2 = r02[1];
        W1 = r13[0]; W3 = r13[1];
      }
#else
      {
        unsigned int sA0 = (unsigned int)__shfl_xor((int)A0, 32);
        unsigned int sB0 = (unsigned int)__shfl_xor((int)B0, 32);
        unsigned int sA1 = (unsigned int)__shfl_xor((int)A1, 32);
        unsigned int sB1 = (unsigned int)__shfl_xor((int)B1, 32);
        W0 = h ? sB0 : A0;  W2 = h ? B0 : sA0;
        W1 = h ? sB1 : A1;  W3 = h ? B1 : sA1;
      }
#endif
      uint4 uw = { W0, W1, W2, W3 };
      bf16x8 pa = __builtin_bit_cast(bf16x8, uw);
      __builtin_amdgcn_s_setprio(1);
#pragma unroll
      for (int dh = 0; dh < 2; ++dh) {
        bf16x8 vf = *(const bf16x8*)&lds_v[half][swz(dh * 32 + l31, c * 16 + h * 8)];
        if (dh == 0)
          acc0 = __builtin_amdgcn_mfma_f32_32x32x16_bf16(pa, vf, acc0, 0, 0, 0);
        else
          acc1 = __builtin_amdgcn_mfma_f32_32x32x16_bf16(pa, vf, acc1, 0, 0, 0);
      }
      __builtin_amdgcn_s_setprio(0);
    }
  }

  // ---- split-KV merge: half=1 -> LDS (overlay staging bufs), half=0 reads ----
  float* accb0 = reinterpret_cast<float*>(lds_k);  // [4][64][16]
  float* accb1 = reinterpret_cast<float*>(lds_v);  // [4][64][16]
  __syncthreads();                                 // staging reads all done
  if (half == 1) {
    lds_ml[pr][lane][0] = mL2;
    lds_ml[pr][lane][1] = lsum;
    float* a0 = &accb0[(pr * 64 + lane) * 16];
    float* a1 = &accb1[(pr * 64 + lane) * 16];
#pragma unroll
    for (int r = 0; r < 16; ++r) { a0[r] = acc0[r]; a1[r] = acc1[r]; }
  }
  __syncthreads();
  if (half == 0) {
    const float mB = lds_ml[pr][lane][0];
    const float lB = lds_ml[pr][lane][1];
    const float mst = fmaxf(mL2, mB);
    float fA, fB;
    if (mst == -INFINITY) { fA = 0.0f; fB = 0.0f; }
    else { fA = exp2f(mL2 - mst); fB = exp2f(mB - mst); }
    const float lm = lsum * fA + lB * fB;
    const float li = 1.0f / lm;
    const float* a0 = &accb0[(pr * 64 + lane) * 16];
    const float* a1 = &accb1[(pr * 64 + lane) * 16];
#pragma unroll
    for (int r = 0; r < 16; ++r) {
      const int mrow = (r & 3) + 8 * (r >> 2) + 4 * h;
      const float fAr = __shfl(fA, mrow);   // factors are per-q-row
      const float fBr = __shfl(fB, mrow);
      const float lr  = __shfl(li, mrow);
      const float o0 = (acc0[r] * fAr + a0[r] * fBr) * lr;
      const float o1 = (acc1[r] * fAr + a1[16 * 0 + r] * fBr) * lr;   // a1[r]
      float* op = O + (size_t)(qrow_w + mrow) * D_DIM + l31;
      op[0]  = o0;
      op[32] = o1;
    }
  }
}

extern "C" void kernel_launch(void* const* d_in, const int* in_sizes, int n_in,
                              void* d_out, int out_size, void* d_ws, size_t ws_size,
                              hipStream_t stream) {
  const float* q = (const float*)d_in[0];
  const float* k = (const float*)d_in[1];
  const float* v = (const float*)d_in[2];
  // d_in[3] (causal mask) is deterministic tril -> computed in-kernel.
  float* o = (float*)d_out;
  attn_fwd_kernel<<<512, NTH, 0, stream>>>(q, k, v, o);
}

// Round 11
// 85.122 us; speedup vs baseline: 7.1522x; 1.2889x over previous
//
#include <hip/hip_runtime.h>
#include <hip/hip_bf16.h>
#include <math.h>

// Causal SDPA, B=2 H=16 S=2048 D=64, fp32 in/out.
// v9 = v5 (best, 83us) + two proven wins, spill-safe:
//  - XCD-affine 1D grid (v7: FETCH 116->24.6 MB), 4 heads/XCD, descending q
//  - LDS double-buffer, ONE barrier/iter: stage(buf^1,it+1) before compute,
//    direct global->cvt->ds_write (no reg block -> no v8 spills)
//  - T5 setprio around MFMA clusters
// Waves: 8 = 4 q-strips x 2 kv-halves. KVBLK=64/half. 32x32x16 MFMA,
// swapped QK^T, in-reg P (T12), deferred rescale (T13), swizzled LDS.

#define S_LEN 2048
#define D_DIM 64
#define NTH   512
#define L2E   1.4426950408889634f
#define THRL2 11.5f

typedef float f32x16 __attribute__((ext_vector_type(16)));
typedef __bf16 bf16x8 __attribute__((ext_vector_type(8)));
typedef __bf16 bf16x4 __attribute__((ext_vector_type(4)));
typedef unsigned int uint2v __attribute__((ext_vector_type(2)));

static __device__ inline unsigned int cvtpk(float lo, float hi) {
  unsigned int r;
  asm("v_cvt_pk_bf16_f32 %0, %1, %2" : "=v"(r) : "v"(lo), "v"(hi));
  return r;
}
// swizzled element offset in a [rows][64] bf16 LDS tile (128B rows)
static __device__ inline int swz(int row, int col) {
  return row * 64 + ((((col >> 3) ^ (row & 7)) << 3) | (col & 7));
}

__global__ __launch_bounds__(NTH, 4) void attn_fwd_kernel(
    const float* __restrict__ Qg, const float* __restrict__ Kg,
    const float* __restrict__ Vg, float* __restrict__ Og) {
  __shared__ unsigned short lds_k[2][2][64 * 64];  // [half][buf] K[kv][d]
  __shared__ unsigned short lds_v[2][2][64 * 64];  // [half][buf] V^T[d][kv]
  __shared__ float lds_ml[4][64][2];               // merge m,l (half=1)

  const int t = threadIdx.x;
  const int lane = t & 63, w = t >> 6, l31 = lane & 31, h = lane >> 5;
  const int wq = w & 3, half = w >> 2;  // q-strip 0..3, kv half 0..1
  const int tl = t & 255;               // staging index within half group

  const int wgid = (int)blockIdx.x;
  const int xcd = wgid & 7, idx = wgid >> 3;       // 64 blocks per XCD
  const int bh = xcd * 4 + (idx >> 4);             // 4 heads per XCD
  const int q0 = (15 - (idx & 15)) * 128;          // descending q (big first)
  const size_t base = (size_t)bh * S_LEN * D_DIM;
  const float* Q = Qg + base;
  const float* K = Kg + base;
  const float* V = Vg + base;
  float*       O = Og + base;

  const int qrow_w = q0 + wq * 32;
  const int qg = qrow_w + l31;          // this lane's q-row

  // ---- staging coords ----
  const int srow = tl >> 4, sc4 = (tl & 15) * 4;   // K stage
  const int d2 = (tl & 31) * 2, kvq = tl >> 5;     // V stage

  auto stage = [&](int buf, int itx) {
    const int kv0s = itx * 128 + half * 64;
#pragma unroll
    for (int pass = 0; pass < 4; ++pass) {
      float4 f = *(const float4*)(K + (size_t)(kv0s + pass * 16 + srow) * D_DIM + sc4);
      bf16x4 k4;
      k4[0] = (__bf16)f.x; k4[1] = (__bf16)f.y;
      k4[2] = (__bf16)f.z; k4[3] = (__bf16)f.w;
      *(bf16x4*)&lds_k[half][buf][swz(pass * 16 + srow, sc4)] = k4;
    }
    bf16x8 bx, by;
#pragma unroll
    for (int i = 0; i < 8; ++i) {
      float2 vv = *(const float2*)(V + (size_t)(kv0s + kvq * 8 + i) * D_DIM + d2);
      bx[i] = (__bf16)vv.x;
      by[i] = (__bf16)vv.y;
    }
    *(bf16x8*)&lds_v[half][buf][swz(d2, kvq * 8)]     = bx;
    *(bf16x8*)&lds_v[half][buf][swz(d2 + 1, kvq * 8)] = by;
  };

  // ---- Q fragments (B operand: col q = lane&31, k = h*8+j), x0.125 ----
  bf16x8 qf[4];
  {
    const float* qp = Q + (size_t)qg * D_DIM + h * 8;
#pragma unroll
    for (int kc = 0; kc < 4; ++kc) {
      float4 a = *(const float4*)(qp + kc * 16);
      float4 b = *(const float4*)(qp + kc * 16 + 4);
      bf16x8 q8;
      q8[0] = (__bf16)(a.x * 0.125f); q8[1] = (__bf16)(a.y * 0.125f);
      q8[2] = (__bf16)(a.z * 0.125f); q8[3] = (__bf16)(a.w * 0.125f);
      q8[4] = (__bf16)(b.x * 0.125f); q8[5] = (__bf16)(b.y * 0.125f);
      q8[6] = (__bf16)(b.z * 0.125f); q8[7] = (__bf16)(b.w * 0.125f);
      qf[kc] = q8;
    }
  }

  float mL2 = -INFINITY, lsum = 0.0f;   // per-lane (q = l31) softmax state
  f32x16 acc0 = (f32x16)0.0f, acc1 = (f32x16)0.0f;   // O[32q][32d] halves

  const int nit = q0 / 128 + 1;         // 128-wide kv super-tiles
  stage(0, 0);
  __syncthreads();                      // buf 0 ready

  for (int it = 0; it < nit; ++it) {
    const int cur = it & 1;
    // ---- stage next tile into the other buffer (overlaps compute) ----
    if (it + 1 < nit) stage(cur ^ 1, it + 1);

    const int kv0 = it * 128 + half * 64;
    if (kv0 <= qrow_w + 31) {           // else fully masked for this wave
      // ---- S^T = K·Q^T : D[32kv][32q] x2 tiles, lane owns col q = l31 ----
      f32x16 st[2];
      st[0] = (f32x16)0.0f; st[1] = (f32x16)0.0f;
      __builtin_amdgcn_s_setprio(1);
#pragma unroll
      for (int kc = 0; kc < 4; ++kc) {
#pragma unroll
        for (int mt = 0; mt < 2; ++mt) {
          bf16x8 kf = *(const bf16x8*)&lds_k[half][cur][swz(mt * 32 + l31, kc * 16 + h * 8)];
          st[mt] = __builtin_amdgcn_mfma_f32_32x32x16_bf16(kf, qf[kc], st[mt], 0, 0, 0);
        }
      }
      __builtin_amdgcn_s_setprio(0);

      // ---- causal mask (diagonal tiles only) + row max ----
      float tm = -INFINITY;
      if (kv0 + 63 > qrow_w) {          // tile touches the diagonal
#pragma unroll
        for (int mt = 0; mt < 2; ++mt)
#pragma unroll
          for (int r = 0; r < 16; ++r) {
            int kv = kv0 + mt * 32 + (r & 3) + 8 * (r >> 2) + 4 * h;
            float sv = (kv <= qg) ? st[mt][r] : -INFINITY;
            st[mt][r] = sv;
            tm = fmaxf(tm, sv);
          }
      } else {
#pragma unroll
        for (int mt = 0; mt < 2; ++mt)
#pragma unroll
          for (int r = 0; r < 16; ++r) tm = fmaxf(tm, st[mt][r]);
      }
      tm = fmaxf(tm, __shfl_xor(tm, 32));
      const float tmL2 = tm * L2E;

      // ---- deferred rescale (T13) ----
      if (__any(tmL2 - mL2 > THRL2)) {
        const float mn = fmaxf(mL2, tmL2);
        const float f  = exp2f(mL2 - mn);
        lsum *= f;
        mL2 = mn;
#pragma unroll
        for (int r = 0; r < 16; ++r) {
          const int mrow = (r & 3) + 8 * (r >> 2) + 4 * h;
          const float fr = __shfl(f, mrow);
          acc0[r] *= fr;
          acc1[r] *= fr;
        }
      }

      // ---- P = exp2(S*L2E - m); row sum ----
      float ps = 0.0f;
#pragma unroll
      for (int mt = 0; mt < 2; ++mt)
#pragma unroll
        for (int r = 0; r < 16; ++r) {
          float pv = exp2f(fmaf(st[mt][r], L2E, -mL2));
          st[mt][r] = pv;
          ps += pv;
        }
      ps += __shfl_xor(ps, 32);
      lsum += ps;

      // ---- PV: in-register A-frag via cvt_pk + permlane32_swap (T12) ----
#pragma unroll
      for (int c = 0; c < 4; ++c) {
        const int rb = 8 * (c & 1);
        const int m2 = c >> 1;
        unsigned int A0 = cvtpk(st[m2][rb + 0], st[m2][rb + 1]);
        unsigned int A1 = cvtpk(st[m2][rb + 2], st[m2][rb + 3]);
        unsigned int B0 = cvtpk(st[m2][rb + 4], st[m2][rb + 5]);
        unsigned int B1 = cvtpk(st[m2][rb + 6], st[m2][rb + 7]);
        unsigned int W0, W1, W2, W3;
#if __has_builtin(__builtin_amdgcn_permlane32_swap)
        {
          uint2v r02 = __builtin_amdgcn_permlane32_swap(A0, B0, false, false);
          uint2v r13 = __builtin_amdgcn_permlane32_swap(A1, B1, false, false);
          W0 = r02[0]; W2 = r02[1];
          W1 = r13[0]; W3 = r13[1];
        }
#else
        {
          unsigned int sA0 = (unsigned int)__shfl_xor((int)A0, 32);
          unsigned int sB0 = (unsigned int)__shfl_xor((int)B0, 32);
          unsigned int sA1 = (unsigned int)__shfl_xor((int)A1, 32);
          unsigned int sB1 = (unsigned int)__shfl_xor((int)B1, 32);
          W0 = h ? sB0 : A0;  W2 = h ? B0 : sA0;
          W1 = h ? sB1 : A1;  W3 = h ? B1 : sA1;
        }
#endif
        uint4 uw = { W0, W1, W2, W3 };
        bf16x8 pa = __builtin_bit_cast(bf16x8, uw);
        __builtin_amdgcn_s_setprio(1);
#pragma unroll
        for (int dh = 0; dh < 2; ++dh) {
          bf16x8 vf = *(const bf16x8*)&lds_v[half][cur][swz(dh * 32 + l31, c * 16 + h * 8)];
          if (dh == 0)
            acc0 = __builtin_amdgcn_mfma_f32_32x32x16_bf16(pa, vf, acc0, 0, 0, 0);
          else
            acc1 = __builtin_amdgcn_mfma_f32_32x32x16_bf16(pa, vf, acc1, 0, 0, 0);
        }
        __builtin_amdgcn_s_setprio(0);
      }
    }
    __syncthreads();   // next buf staged AND cur reads done (all waves reach)
  }

  // ---- split-KV merge: half=1 -> LDS (overlay staging bufs), half=0 reads ----
  float* accb0 = reinterpret_cast<float*>(lds_k);  // [4][64][16]
  float* accb1 = reinterpret_cast<float*>(lds_v);  // [4][64][16]
  if (half == 1) {
    lds_ml[wq][lane][0] = mL2;
    lds_ml[wq][lane][1] = lsum;
    float* a0 = &accb0[(wq * 64 + lane) * 16];
    float* a1 = &accb1[(wq * 64 + lane) * 16];
#pragma unroll
    for (int r = 0; r < 16; ++r) { a0[r] = acc0[r]; a1[r] = acc1[r]; }
  }
  __syncthreads();
  if (half == 0) {
    const float mB = lds_ml[wq][lane][0];
    const float lB = lds_ml[wq][lane][1];
    const float mst = fmaxf(mL2, mB);
    float fA, fB;
    if (mst == -INFINITY) { fA = 0.0f; fB = 0.0f; }
    else { fA = exp2f(mL2 - mst); fB = exp2f(mB - mst); }
    const float lm = lsum * fA + lB * fB;
    const float li = 1.0f / lm;
    const float* a0 = &accb0[(wq * 64 + lane) * 16];
    const float* a1 = &accb1[(wq * 64 + lane) * 16];
#pragma unroll
    for (int r = 0; r < 16; ++r) {
      const int mrow = (r & 3) + 8 * (r >> 2) + 4 * h;
      const float fAr = __shfl(fA, mrow);   // factors are per-q-row
      const float fBr = __shfl(fB, mrow);
      const float lr  = __shfl(li, mrow);
      const float o0 = (acc0[r] * fAr + a0[r] * fBr) * lr;
      const float o1 = (acc1[r] * fAr + a1[r] * fBr) * lr;
      float* op = O + (size_t)(qrow_w + mrow) * D_DIM + l31;
      op[0]  = o0;
      op[32] = o1;
    }
  }
}

extern "C" void kernel_launch(void* const* d_in, const int* in_sizes, int n_in,
                              void* d_out, int out_size, void* d_ws, size_t ws_size,
                              hipStream_t stream) {
  const float* q = (const float*)d_in[0];
  const float* k = (const float*)d_in[1];
  const float* v = (const float*)d_in[2];
  // d_in[3] (causal mask) is deterministic tril -> computed in-kernel.
  float* o = (float*)d_out;
  attn_fwd_kernel<<<512, NTH, 0, stream>>>(q, k, v, o);
}